// Round 6
// baseline (202.516 us; speedup 1.0000x reference)
//
#include <hip/hip_runtime.h>
#include <hip/hip_fp16.h>

#define F_IN 128
#define HID  64
#define CAP  96      // max edges per dst node (degrees ~Poisson(16), max ~45)
#define CSHIFT 9     // coarse bucket = dst >> 9 (512 nodes per bucket)
#define CNODES 512
#define NC_MAX 256   // >= ceil(N/512)
#define CCHUNK 4096  // edges per coarse-bin block
#define BCAPC 8960   // entries per coarse bucket (mean 8163, +8 sigma)

typedef short s16x8 __attribute__((ext_vector_type(8)));   // 8 bf16 (4 VGPRs) MFMA operand
typedef float f32x4 __attribute__((ext_vector_type(4)));   // MFMA accumulator

// bf16 round-to-nearest-even, pure int ops (no __bf16 dependence)
__device__ inline unsigned short bf16rne(float f) {
    unsigned u = __float_as_uint(f);
    return (unsigned short)((u + 0x7FFFu + ((u >> 16) & 1u)) >> 16);
}
__device__ inline float bf16tof(unsigned short h) {
    return __uint_as_float(((unsigned)h) << 16);
}

// ---------------- Pass A: coarse bin (196 buckets), direct global scatter ----------------
__launch_bounds__(256)
__global__ void k_coarse(const int* __restrict__ src, const int* __restrict__ dst,
                         int* __restrict__ acur, int* __restrict__ ent, int E, int nc) {
    __shared__ int s_cnt[NC_MAX];
    __shared__ int s_gb[NC_MAX];
    __shared__ int s_bump[NC_MAX];
    int t = threadIdx.x;
    int e0 = blockIdx.x * CCHUNK;
    int n = E - e0; if (n > CCHUNK) n = CCHUNK;

    for (int i = t; i < nc; i += 256) { s_cnt[i] = 0; s_bump[i] = 0; }
    __syncthreads();
    for (int i = t; i < n; i += 256)
        atomicAdd(&s_cnt[dst[e0 + i] >> CSHIFT], 1);
    __syncthreads();
    if (t < nc) {
        int c = s_cnt[t];
        s_gb[t] = (c > 0) ? atomicAdd(&acur[t], c) : 0;
    }
    __syncthreads();
    for (int i = t; i < n; i += 256) {
        int d = dst[e0 + i], s = src[e0 + i];
        int b = d >> CSHIFT;
        int p = s_gb[b] + atomicAdd(&s_bump[b], 1);
        if (p < BCAPC) ent[(size_t)b * BCAPC + p] = (s << CSHIFT) | (d & (CNODES - 1));
    }
}

// ---------------- Pass B: per-coarse-bucket regroup into per-node CSR ----------------
__launch_bounds__(1024)
__global__ void k_fillc(const int* __restrict__ acur, const int* __restrict__ ent,
                        int* __restrict__ counts, int* __restrict__ csrc, int N) {
    __shared__ int lcnt[CNODES];
    int b = blockIdx.x, t = threadIdx.x;
    if (t < CNODES) lcnt[t] = 0;
    __syncthreads();
    int base = b * CNODES;
    int cnt = acur[b]; if (cnt > BCAPC) cnt = BCAPC;
    const int* ep = ent + (size_t)b * BCAPC;
    for (int i = t; i < cnt; i += 1024) {
        int v = ep[i];
        int ld = v & (CNODES - 1), s = v >> CSHIFT;
        int p = atomicAdd(&lcnt[ld], 1);
        if (p < CAP) csrc[(size_t)(base + ld) * CAP + p] = s;
    }
    __syncthreads();
    if (t < CNODES && base + t < N) {
        int cc = lcnt[t]; if (cc > CAP) cc = CAP;
        counts[base + t] = cc;
    }
}

// ---------------- W1 split: fp32 [128][64] -> two bf16 transposed copies [64][128] ----------------
// (xh+xl)(wh+wl) summed over 4 MFMAs == product of inputs represented to 2^-18 rel -> fp32-quality.
__launch_bounds__(256)
__global__ void k_wsplit(const float* __restrict__ W1, unsigned short* __restrict__ W1hT,
                         unsigned short* __restrict__ W1lT) {
    int id = blockIdx.x * 256 + threadIdx.x;   // 0..8191 ; id = k*64 + c
    int k = id >> 6, c = id & 63;
    float f = W1[id];
    unsigned short h = bf16rne(f);
    unsigned short l = bf16rne(f - bf16tof(h));
    W1hT[c * F_IN + k] = h;
    W1lT[c * F_IN + k] = l;
}

// ---------------- GEMM via MFMA: hn = fp16( (x @ W1) * dinv(row) ) ----------------
// 4 waves/block, each wave = 16 rows x 64 cols, no LDS, no barriers.
// A: lane(r=lane&15, q=lane>>4) reads x[row r][kt*32+q*8 ..+7] as fp32 (wave's 64 lanes
//    exactly cover 32 full 64B lines -> fully utilized fetch) then splits to bf16 hi/lo.
// B: 16B loads from the 16KB L1-resident W1hT/W1lT (col=lane&15, k contiguous).
// 4-term split: acc += ah*bh + al*bh + ah*bl + al*bl  (fp32 MFMA accumulate).
// D layout: col = lane&15 (+nt*16), row = r0w + (lane>>4)*4 + reg.
__launch_bounds__(256)
__global__ void k_gemm(const float* __restrict__ x,
                       const unsigned short* __restrict__ W1hT,
                       const unsigned short* __restrict__ W1lT,
                       const int* __restrict__ counts, __half* __restrict__ hn, int N) {
    int t = threadIdx.x;
    int lane = t & 63;
    int wid = t >> 6;
    int r0w = blockIdx.x * 64 + wid * 16;     // wave's 16-row base
    int arow = r0w + (lane & 15);
    int ar = (arow < N) ? arow : (N - 1);     // clamp; out-of-range rows never stored
    int kq = lane >> 4;                        // k-quarter 0..3

    const float* xr = x + (size_t)ar * F_IN + kq * 8;
    int coff = (lane & 15) * F_IN + kq * 8;    // elem offset in [col][k] bf16 layout

    f32x4 acc[4];
#pragma unroll
    for (int nt = 0; nt < 4; ++nt) acc[nt] = (f32x4){0.f, 0.f, 0.f, 0.f};

#pragma unroll
    for (int kt = 0; kt < 4; ++kt) {
        float4 xa = *(const float4*)(xr + kt * 32);
        float4 xb = *(const float4*)(xr + kt * 32 + 4);
        float xf[8] = {xa.x, xa.y, xa.z, xa.w, xb.x, xb.y, xb.z, xb.w};
        s16x8 ah, al;
#pragma unroll
        for (int j = 0; j < 8; ++j) {
            unsigned short h = bf16rne(xf[j]);
            ah[j] = (short)h;
            al[j] = (short)bf16rne(xf[j] - bf16tof(h));
        }
        int kb = coff + kt * 32;
#pragma unroll
        for (int nt = 0; nt < 4; ++nt) {
            s16x8 bh = *(const s16x8*)(W1hT + nt * 16 * F_IN + kb);
            s16x8 bl = *(const s16x8*)(W1lT + nt * 16 * F_IN + kb);
            acc[nt] = __builtin_amdgcn_mfma_f32_16x16x32_bf16(ah, bh, acc[nt], 0, 0, 0);
            acc[nt] = __builtin_amdgcn_mfma_f32_16x16x32_bf16(al, bh, acc[nt], 0, 0, 0);
            acc[nt] = __builtin_amdgcn_mfma_f32_16x16x32_bf16(ah, bl, acc[nt], 0, 0, 0);
            acc[nt] = __builtin_amdgcn_mfma_f32_16x16x32_bf16(al, bl, acc[nt], 0, 0, 0);
        }
    }

    int rbase = r0w + (lane >> 4) * 4;        // D rows this lane owns
    if (rbase >= N) return;
    int4 c4 = *(const int4*)(counts + rbase); // 16B-aligned; alloc slack covers tail
    int cj[4] = {c4.x, c4.y, c4.z, c4.w};
#pragma unroll
    for (int j = 0; j < 4; ++j) {
        int row = rbase + j;
        if (row < N) {
            float di = rsqrtf((float)(cj[j] + 1));
            __half* hp = hn + (size_t)row * HID + (lane & 15);
#pragma unroll
            for (int nt = 0; nt < 4; ++nt)
                hp[nt * 16] = __float2half_rn(acc[nt][j] * di);
        }
    }
}

// ---------------- layer 1 gather (fp16 rows) + self-loop + bias + ReLU + @W2 ----------------
// 2 nodes/wave (32 lanes each), 8 lanes x 16B (dwordx4) per 128B fp16 row, 4 edge groups
// per node. One load instruction serves 8 rows (4 groups x 2 nodes). First 16 edges are
// branchless (invalid slots -> own row, weight 0); the 16..32 chunk is guarded by a
// WAVE-UNIFORM branch on cmax = max(cntA, cntB); deg>32 is a rare uniform loop.
__device__ inline void accum8(float acc[8], int4 raw, float w) {
    int v[4] = { raw.x, raw.y, raw.z, raw.w };
#pragma unroll
    for (int h = 0; h < 4; ++h) {
        __half2 h2 = *(__half2*)&v[h];
        float2 f = __half22float2(h2);
        acc[2 * h]     = fmaf(w, f.x, acc[2 * h]);
        acc[2 * h + 1] = fmaf(w, f.y, acc[2 * h + 1]);
    }
}

__launch_bounds__(256)
__global__ void k_gather1(const int* __restrict__ csrc, const int* __restrict__ counts,
                          const __half* __restrict__ hn, const float* __restrict__ b1,
                          const float* __restrict__ W2, float* __restrict__ zn, int N) {
    int lane = threadIdx.x & 63;
    int g    = (lane >> 3) & 3;    // edge group 0..3 within the node's 32 lanes
    int li   = lane & 7;           // 16B chunk within the 128B fp16 row
    // node: wave handles 2 nodes; lanes 0-31 -> node A, 32-63 -> node B
    int r = blockIdx.x * 8 + ((threadIdx.x >> 6) << 1) + (lane >> 5);
    int rr = (r < N) ? r : (N - 1);              // clamp: keep all lanes active (shfl safety)
    int cnt = (r < N) ? counts[rr] : 0;

    const int4* cs4 = (const int4*)(csrc + (size_t)rr * CAP);  // 16B-aligned
    size_t lo = (size_t)li * 8;   // half offset within the 64-half row (li*16 bytes)

    float acc[8];
#pragma unroll
    for (int c = 0; c < 8; ++c) acc[c] = 0.f;

    // ---- chunk A: edges 4g+k, k=0..3 (covers 0..15) — fully branchless ----
    {
        int4 sA = cs4[g];
        int idx[4]; float w[4];
        idx[0] = sA.x; idx[1] = sA.y; idx[2] = sA.z; idx[3] = sA.w;
#pragma unroll
        for (int k = 0; k < 4; ++k) {
            int e = 4 * g + k;
            bool v = (e < cnt);
            idx[k] = v ? idx[k] : rr;   // invalid: own row (cached), weight 0
            w[k]   = v ? 1.f : 0.f;
        }
        int4 raw[4];
#pragma unroll
        for (int k = 0; k < 4; ++k)
            raw[k] = *(const int4*)&hn[(size_t)idx[k] * HID + lo];
#pragma unroll
        for (int k = 0; k < 4; ++k) accum8(acc, raw[k], w[k]);
    }

    // wave-uniform upper bound over both nodes -> scalar branches below
    int cntO = __shfl_xor(cnt, 32, 64);
    int cmax = (cnt > cntO) ? cnt : cntO;

    // ---- chunk B: edges 16+4g+k (covers 16..31), skipped by ~32% of waves ----
    if (cmax > 16) {
        int4 sB = cs4[4 + g];
        int idx[4]; float w[4];
        idx[0] = sB.x; idx[1] = sB.y; idx[2] = sB.z; idx[3] = sB.w;
#pragma unroll
        for (int k = 0; k < 4; ++k) {
            int e = 16 + 4 * g + k;
            bool v = (e < cnt);
            idx[k] = v ? idx[k] : rr;
            w[k]   = v ? 1.f : 0.f;
        }
        int4 raw[4];
#pragma unroll
        for (int k = 0; k < 4; ++k)
            raw[k] = *(const int4*)&hn[(size_t)idx[k] * HID + lo];
#pragma unroll
        for (int k = 0; k < 4; ++k) accum8(acc, raw[k], w[k]);
    }

    // ---- rare tail: deg > 32 (Poisson(16) tail ~1e-4), uniform loop ----
    for (int c = 32; c < cmax; c += 16) {
        int4 s = cs4[(c >> 2) + g];
        int idx[4]; float w[4];
        idx[0] = s.x; idx[1] = s.y; idx[2] = s.z; idx[3] = s.w;
#pragma unroll
        for (int k = 0; k < 4; ++k) {
            int e = c + 4 * g + k;
            bool v = (e < cnt);
            idx[k] = v ? idx[k] : rr;
            w[k]   = v ? 1.f : 0.f;
        }
        int4 raw[4];
#pragma unroll
        for (int k = 0; k < 4; ++k)
            raw[k] = *(const int4*)&hn[(size_t)idx[k] * HID + lo];
#pragma unroll
        for (int k = 0; k < 4; ++k) accum8(acc, raw[k], w[k]);
    }

    // ---- reduce across the 4 edge groups (lane bits 3..4; stays within each 32-half) ----
#pragma unroll
    for (int c = 0; c < 8; ++c) {
        acc[c] += __shfl_xor(acc[c], 8, 64);
        acc[c] += __shfl_xor(acc[c], 16, 64);
    }

    // ---- self-loop row + bias + ReLU + dot with W2 ----
    int4 rawR = *(const int4*)&hn[(size_t)rr * HID + lo];
    accum8(acc, rawR, 1.f);

    float di = rsqrtf((float)(cnt + 1));
    float4 b0 = *(const float4*)&b1[li * 8];
    float4 b4 = *(const float4*)&b1[li * 8 + 4];
    float4 w0 = *(const float4*)&W2[li * 8];
    float4 w4 = *(const float4*)&W2[li * 8 + 4];

    float p = fmaxf(fmaf(di, acc[0], b0.x), 0.f) * w0.x
            + fmaxf(fmaf(di, acc[1], b0.y), 0.f) * w0.y
            + fmaxf(fmaf(di, acc[2], b0.z), 0.f) * w0.z
            + fmaxf(fmaf(di, acc[3], b0.w), 0.f) * w0.w
            + fmaxf(fmaf(di, acc[4], b4.x), 0.f) * w4.x
            + fmaxf(fmaf(di, acc[5], b4.y), 0.f) * w4.y
            + fmaxf(fmaf(di, acc[6], b4.z), 0.f) * w4.z
            + fmaxf(fmaf(di, acc[7], b4.w), 0.f) * w4.w;

    // sum over the 8 li-lanes (bits 0..2; stays within each 32-half)
    p += __shfl_xor(p, 1, 64);
    p += __shfl_xor(p, 2, 64);
    p += __shfl_xor(p, 4, 64);

    if ((lane & 31) == 0 && r < N) zn[r] = p * di;
}

// ---------------- layer 2 gather: 16 lanes per node ----------------
__global__ void k_gather2(const int* __restrict__ csrc, const int* __restrict__ counts,
                          const float* __restrict__ zn, const float* __restrict__ b2,
                          float* __restrict__ out, int N) {
    int t = blockIdx.x * blockDim.x + threadIdx.x;
    int r = t >> 4, li = t & 15;
    if (r >= N) return;
    size_t beg = (size_t)r * CAP;
    int cnt = counts[r];
    float acc = 0.f;
    for (int j = li; j < cnt; j += 16) {
        acc += zn[csrc[beg + j]];
    }
    acc += __shfl_xor(acc, 1, 64);
    acc += __shfl_xor(acc, 2, 64);
    acc += __shfl_xor(acc, 4, 64);
    acc += __shfl_xor(acc, 8, 64);
    if (li == 0) {
        float di = rsqrtf((float)(cnt + 1));
        out[r] = di * (acc + zn[r]) + b2[0];
    }
}

extern "C" void kernel_launch(void* const* d_in, const int* in_sizes, int n_in,
                              void* d_out, int out_size, void* d_ws, size_t ws_size,
                              hipStream_t stream) {
    const float* x  = (const float*)d_in[0];
    const int*   ei = (const int*)d_in[1];   // [2, E] int32
    const float* W1 = (const float*)d_in[2];
    const float* b1 = (const float*)d_in[3];
    const float* W2 = (const float*)d_in[4];
    const float* b2 = (const float*)d_in[5];
    float* out = (float*)d_out;

    const int N = in_sizes[0] / F_IN;     // 100000
    const int E = in_sizes[1] / 2;        // 1600000
    const int* src = ei;
    const int* dst = ei + E;

    const int nc = (N + CNODES - 1) / CNODES;   // 196 coarse buckets
    const int NBKT = (N + 63) / 64;             // 1563 gemm blocks

    // workspace layout (all 256B-aligned)
    char* ws = (char*)d_ws;
    size_t off = 0;
    auto alloc = [&](size_t bytes) { void* p = ws + off; off += (bytes + 255) & ~255ULL; return p; };
    int*    acur   = (int*)   alloc((size_t)nc * 4);
    int*    counts = (int*)   alloc((size_t)N * 4);
    float*  zn     = (float*) alloc((size_t)N * 4);
    unsigned short* W1hT = (unsigned short*) alloc((size_t)HID * F_IN * 2);  // 16 KB
    unsigned short* W1lT = (unsigned short*) alloc((size_t)HID * F_IN * 2);  // 16 KB
    int*    ent    = (int*)   alloc((size_t)nc * BCAPC * 4);  // 7.0 MB
    __half* hn     = (__half*)alloc((size_t)N * HID * 2);     // 12.8 MB
    int*    csrc   = (int*)   alloc((size_t)N * CAP * 4);     // 38.4 MB

    hipMemsetAsync(acur, 0, (size_t)nc * 4, stream);

    const int coarseBlks = (E + CCHUNK - 1) / CCHUNK;   // 391
    k_wsplit<<<32, 256, 0, stream>>>(W1, W1hT, W1lT);
    k_coarse<<<coarseBlks, 256, 0, stream>>>(src, dst, acur, ent, E, nc);
    k_fillc<<<nc, 1024, 0, stream>>>(acur, ent, counts, csrc, N);
    k_gemm<<<NBKT, 256, 0, stream>>>(x, W1hT, W1lT, counts, hn, N);
    k_gather1<<<(N + 7) / 8, 256, 0, stream>>>(csrc, counts, hn, b1, W2, zn, N);
    k_gather2<<<((size_t)N * 16 + 255) / 256, 256, 0, stream>>>(csrc, counts, zn, b2, out, N);
}

// Round 7
// 200.826 us; speedup vs baseline: 1.0084x; 1.0084x over previous
//
#include <hip/hip_runtime.h>
#include <hip/hip_fp16.h>

#define F_IN 128
#define HID  64
#define CAP  96      // max edges per dst node (degrees ~Poisson(16), max ~45)
#define CSHIFT 9     // coarse bucket = dst >> 9 (512 nodes per bucket)
#define CNODES 512
#define NC_MAX 256   // >= ceil(N/512)
#define CCHUNK 4096  // edges per coarse-bin block
#define BCAPC 8960   // entries per coarse bucket (mean 8163, +8 sigma)

typedef short s16x8 __attribute__((ext_vector_type(8)));   // 8 bf16 (4 VGPRs) MFMA operand
typedef float f32x4 __attribute__((ext_vector_type(4)));   // MFMA accumulator

// bf16 round-to-nearest-even, pure int ops (no __bf16 dependence)
__device__ inline unsigned short bf16rne(float f) {
    unsigned u = __float_as_uint(f);
    return (unsigned short)((u + 0x7FFFu + ((u >> 16) & 1u)) >> 16);
}
__device__ inline float bf16tof(unsigned short h) {
    return __uint_as_float(((unsigned)h) << 16);
}

// ---------------- Pass A: coarse bin (196 buckets), direct global scatter ----------------
// First 32 blocks also perform the W1 hi/lo bf16 split (folded-in k_wsplit; saves a launch).
__launch_bounds__(256)
__global__ void k_coarse(const int* __restrict__ src, const int* __restrict__ dst,
                         int* __restrict__ acur, int* __restrict__ ent, int E, int nc,
                         const float* __restrict__ W1, unsigned short* __restrict__ W1hT,
                         unsigned short* __restrict__ W1lT) {
    __shared__ int s_cnt[NC_MAX];
    __shared__ int s_gb[NC_MAX];
    __shared__ int s_bump[NC_MAX];
    int t = threadIdx.x;

    if (blockIdx.x < 32) {   // W1 split: 32 blocks x 256 threads = 8192 = F_IN*HID
        int id = blockIdx.x * 256 + t;     // id = k*64 + c
        int k = id >> 6, c = id & 63;
        float f = W1[id];
        unsigned short h = bf16rne(f);
        unsigned short l = bf16rne(f - bf16tof(h));
        W1hT[c * F_IN + k] = h;
        W1lT[c * F_IN + k] = l;
    }

    int e0 = blockIdx.x * CCHUNK;
    int n = E - e0; if (n > CCHUNK) n = CCHUNK;

    for (int i = t; i < nc; i += 256) { s_cnt[i] = 0; s_bump[i] = 0; }
    __syncthreads();
    for (int i = t; i < n; i += 256)
        atomicAdd(&s_cnt[dst[e0 + i] >> CSHIFT], 1);
    __syncthreads();
    if (t < nc) {
        int c = s_cnt[t];
        s_gb[t] = (c > 0) ? atomicAdd(&acur[t], c) : 0;
    }
    __syncthreads();
    for (int i = t; i < n; i += 256) {
        int d = dst[e0 + i], s = src[e0 + i];
        int b = d >> CSHIFT;
        int p = s_gb[b] + atomicAdd(&s_bump[b], 1);
        if (p < BCAPC) ent[(size_t)b * BCAPC + p] = (s << CSHIFT) | (d & (CNODES - 1));
    }
}

// ---------------- Pass B: per-coarse-bucket regroup into per-node CSR ----------------
__launch_bounds__(1024)
__global__ void k_fillc(const int* __restrict__ acur, const int* __restrict__ ent,
                        int* __restrict__ counts, int* __restrict__ csrc, int N) {
    __shared__ int lcnt[CNODES];
    int b = blockIdx.x, t = threadIdx.x;
    if (t < CNODES) lcnt[t] = 0;
    __syncthreads();
    int base = b * CNODES;
    int cnt = acur[b]; if (cnt > BCAPC) cnt = BCAPC;
    const int* ep = ent + (size_t)b * BCAPC;
    for (int i = t; i < cnt; i += 1024) {
        int v = ep[i];
        int ld = v & (CNODES - 1), s = v >> CSHIFT;
        int p = atomicAdd(&lcnt[ld], 1);
        if (p < CAP) csrc[(size_t)(base + ld) * CAP + p] = s;
    }
    __syncthreads();
    if (t < CNODES && base + t < N) {
        int cc = lcnt[t]; if (cc > CAP) cc = CAP;
        counts[base + t] = cc;
    }
}

// ---------------- GEMM via MFMA + LDS-staged A: hn = fp16( (x @ W1) * dinv(row) ) ----------------
// A-path: 64 rows x 512B staged into 32KB LDS via global_load_lds width=16 (coalesced 1KB per
// call, async, drained by the barrier). Row-stride-512B ds_reads would be a 16-way bank
// conflict -> both-sides XOR swizzle (byte ^= (row&7)<<4): inverse-swizzled GLOBAL source
// (tile is contiguous in x) + swizzled ds_read -> 2-way (free). OOB tail rows read row 0.
// B: 16B loads from the 16KB L1-resident W1hT/W1lT. 4-term bf16 split (fp32-quality):
// acc += ah*bh + al*bh + ah*bl + al*bl. D: col=lane&15 (+nt*16), row=r0w+(lane>>4)*4+reg.
__launch_bounds__(256)
__global__ void k_gemm(const float* __restrict__ x,
                       const unsigned short* __restrict__ W1hT,
                       const unsigned short* __restrict__ W1lT,
                       const int* __restrict__ counts, __half* __restrict__ hn, int N) {
    __shared__ float xs[64 * F_IN];   // 32 KB
    int t = threadIdx.x;
    int lane = t & 63;
    int wid = t >> 6;
    int r0 = blockIdx.x * 64;

    // ---- stage: 4 waves x 8 calls x 1KB = 32KB ----
    const char* gbase = (const char*)(x + (size_t)r0 * F_IN);
    int rmax = N - r0;                       // rows available in this tile
#pragma unroll
    for (int c = 0; c < 8; ++c) {
        int base = (wid * 8 + c) * 1024;     // wave-uniform LDS dest base (HW adds lane*16)
        int d = base + lane * 16;            // this lane's dest byte
        int soff = d ^ (((d >> 9) & 7) << 4);  // inverse-swizzled source byte
        if ((soff >> 9) >= rmax) soff &= 511;  // clamp OOB rows (last block) into row 0
        __builtin_amdgcn_global_load_lds(
            (const __attribute__((address_space(1))) unsigned int*)(gbase + soff),
            (__attribute__((address_space(3))) unsigned int*)((char*)xs + base),
            16, 0, 0);
    }
    __syncthreads();

    int lr = lane & 15;
    int q  = lane >> 4;                      // k-quarter 0..3
    int lrow = wid * 16 + lr;                // LDS row this lane reads (A row)
    int swz = (lrow & 7) << 4;
    const char* xrow = (const char*)xs + lrow * 512;

    int r0w = r0 + wid * 16;                 // wave's 16-row base
    int coff = lr * F_IN + q * 8;            // elem offset in [col][k] bf16 layout

    f32x4 acc[4];
#pragma unroll
    for (int nt = 0; nt < 4; ++nt) acc[nt] = (f32x4){0.f, 0.f, 0.f, 0.f};

#pragma unroll
    for (int kt = 0; kt < 4; ++kt) {
        int o  = kt * 128 + q * 32;
        float4 xa = *(const float4*)(xrow + ((o)      ^ swz));
        float4 xb = *(const float4*)(xrow + ((o + 16) ^ swz));
        float xf[8] = {xa.x, xa.y, xa.z, xa.w, xb.x, xb.y, xb.z, xb.w};
        s16x8 ah, al;
#pragma unroll
        for (int j = 0; j < 8; ++j) {
            unsigned short h = bf16rne(xf[j]);
            ah[j] = (short)h;
            al[j] = (short)bf16rne(xf[j] - bf16tof(h));
        }
        int kb = coff + kt * 32;
#pragma unroll
        for (int nt = 0; nt < 4; ++nt) {
            s16x8 bh = *(const s16x8*)(W1hT + nt * 16 * F_IN + kb);
            s16x8 bl = *(const s16x8*)(W1lT + nt * 16 * F_IN + kb);
            acc[nt] = __builtin_amdgcn_mfma_f32_16x16x32_bf16(ah, bh, acc[nt], 0, 0, 0);
            acc[nt] = __builtin_amdgcn_mfma_f32_16x16x32_bf16(al, bh, acc[nt], 0, 0, 0);
            acc[nt] = __builtin_amdgcn_mfma_f32_16x16x32_bf16(ah, bl, acc[nt], 0, 0, 0);
            acc[nt] = __builtin_amdgcn_mfma_f32_16x16x32_bf16(al, bl, acc[nt], 0, 0, 0);
        }
    }

    int rbase = r0w + q * 4;                 // D rows this lane owns
    if (rbase >= N) return;
    int4 c4 = *(const int4*)(counts + rbase); // 16B-aligned; alloc slack covers tail
    int cj[4] = {c4.x, c4.y, c4.z, c4.w};
#pragma unroll
    for (int j = 0; j < 4; ++j) {
        int row = rbase + j;
        if (row < N) {
            float di = rsqrtf((float)(cj[j] + 1));
            __half* hp = hn + (size_t)row * HID + lr;
#pragma unroll
            for (int nt = 0; nt < 4; ++nt)
                hp[nt * 16] = __float2half_rn(acc[nt][j] * di);
        }
    }
}

// ---------------- layer 1 gather (fp16 rows) + self-loop + bias + ReLU + @W2 ----------------
// 2 nodes/wave (32 lanes each), 8 lanes x 16B (dwordx4) per 128B fp16 row, 4 edge groups
// per node. One load instruction serves 8 rows (4 groups x 2 nodes). First 16 edges are
// branchless (invalid slots -> own row, weight 0); the 16..32 chunk is guarded by a
// WAVE-UNIFORM branch on cmax = max(cntA, cntB); deg>32 is a rare uniform loop.
__device__ inline void accum8(float acc[8], int4 raw, float w) {
    int v[4] = { raw.x, raw.y, raw.z, raw.w };
#pragma unroll
    for (int h = 0; h < 4; ++h) {
        __half2 h2 = *(__half2*)&v[h];
        float2 f = __half22float2(h2);
        acc[2 * h]     = fmaf(w, f.x, acc[2 * h]);
        acc[2 * h + 1] = fmaf(w, f.y, acc[2 * h + 1]);
    }
}

__launch_bounds__(256)
__global__ void k_gather1(const int* __restrict__ csrc, const int* __restrict__ counts,
                          const __half* __restrict__ hn, const float* __restrict__ b1,
                          const float* __restrict__ W2, float* __restrict__ zn, int N) {
    int lane = threadIdx.x & 63;
    int g    = (lane >> 3) & 3;    // edge group 0..3 within the node's 32 lanes
    int li   = lane & 7;           // 16B chunk within the 128B fp16 row
    // node: wave handles 2 nodes; lanes 0-31 -> node A, 32-63 -> node B
    int r = blockIdx.x * 8 + ((threadIdx.x >> 6) << 1) + (lane >> 5);
    int rr = (r < N) ? r : (N - 1);              // clamp: keep all lanes active (shfl safety)
    int cnt = (r < N) ? counts[rr] : 0;

    const int4* cs4 = (const int4*)(csrc + (size_t)rr * CAP);  // 16B-aligned
    size_t lo = (size_t)li * 8;   // half offset within the 64-half row (li*16 bytes)

    float acc[8];
#pragma unroll
    for (int c = 0; c < 8; ++c) acc[c] = 0.f;

    // ---- chunk A: edges 4g+k, k=0..3 (covers 0..15) — fully branchless ----
    {
        int4 sA = cs4[g];
        int idx[4]; float w[4];
        idx[0] = sA.x; idx[1] = sA.y; idx[2] = sA.z; idx[3] = sA.w;
#pragma unroll
        for (int k = 0; k < 4; ++k) {
            int e = 4 * g + k;
            bool v = (e < cnt);
            idx[k] = v ? idx[k] : rr;   // invalid: own row (cached), weight 0
            w[k]   = v ? 1.f : 0.f;
        }
        int4 raw[4];
#pragma unroll
        for (int k = 0; k < 4; ++k)
            raw[k] = *(const int4*)&hn[(size_t)idx[k] * HID + lo];
#pragma unroll
        for (int k = 0; k < 4; ++k) accum8(acc, raw[k], w[k]);
    }

    // wave-uniform upper bound over both nodes -> scalar branches below
    int cntO = __shfl_xor(cnt, 32, 64);
    int cmax = (cnt > cntO) ? cnt : cntO;

    // ---- chunk B: edges 16+4g+k (covers 16..31), skipped by ~32% of waves ----
    if (cmax > 16) {
        int4 sB = cs4[4 + g];
        int idx[4]; float w[4];
        idx[0] = sB.x; idx[1] = sB.y; idx[2] = sB.z; idx[3] = sB.w;
#pragma unroll
        for (int k = 0; k < 4; ++k) {
            int e = 16 + 4 * g + k;
            bool v = (e < cnt);
            idx[k] = v ? idx[k] : rr;
            w[k]   = v ? 1.f : 0.f;
        }
        int4 raw[4];
#pragma unroll
        for (int k = 0; k < 4; ++k)
            raw[k] = *(const int4*)&hn[(size_t)idx[k] * HID + lo];
#pragma unroll
        for (int k = 0; k < 4; ++k) accum8(acc, raw[k], w[k]);
    }

    // ---- rare tail: deg > 32 (Poisson(16) tail ~1e-4), uniform loop ----
    for (int c = 32; c < cmax; c += 16) {
        int4 s = cs4[(c >> 2) + g];
        int idx[4]; float w[4];
        idx[0] = s.x; idx[1] = s.y; idx[2] = s.z; idx[3] = s.w;
#pragma unroll
        for (int k = 0; k < 4; ++k) {
            int e = c + 4 * g + k;
            bool v = (e < cnt);
            idx[k] = v ? idx[k] : rr;
            w[k]   = v ? 1.f : 0.f;
        }
        int4 raw[4];
#pragma unroll
        for (int k = 0; k < 4; ++k)
            raw[k] = *(const int4*)&hn[(size_t)idx[k] * HID + lo];
#pragma unroll
        for (int k = 0; k < 4; ++k) accum8(acc, raw[k], w[k]);
    }

    // ---- reduce across the 4 edge groups (lane bits 3..4; stays within each 32-half) ----
#pragma unroll
    for (int c = 0; c < 8; ++c) {
        acc[c] += __shfl_xor(acc[c], 8, 64);
        acc[c] += __shfl_xor(acc[c], 16, 64);
    }

    // ---- self-loop row + bias + ReLU + dot with W2 ----
    int4 rawR = *(const int4*)&hn[(size_t)rr * HID + lo];
    accum8(acc, rawR, 1.f);

    float di = rsqrtf((float)(cnt + 1));
    float4 b0 = *(const float4*)&b1[li * 8];
    float4 b4 = *(const float4*)&b1[li * 8 + 4];
    float4 w0 = *(const float4*)&W2[li * 8];
    float4 w4 = *(const float4*)&W2[li * 8 + 4];

    float p = fmaxf(fmaf(di, acc[0], b0.x), 0.f) * w0.x
            + fmaxf(fmaf(di, acc[1], b0.y), 0.f) * w0.y
            + fmaxf(fmaf(di, acc[2], b0.z), 0.f) * w0.z
            + fmaxf(fmaf(di, acc[3], b0.w), 0.f) * w0.w
            + fmaxf(fmaf(di, acc[4], b4.x), 0.f) * w4.x
            + fmaxf(fmaf(di, acc[5], b4.y), 0.f) * w4.y
            + fmaxf(fmaf(di, acc[6], b4.z), 0.f) * w4.z
            + fmaxf(fmaf(di, acc[7], b4.w), 0.f) * w4.w;

    // sum over the 8 li-lanes (bits 0..2; stays within each 32-half)
    p += __shfl_xor(p, 1, 64);
    p += __shfl_xor(p, 2, 64);
    p += __shfl_xor(p, 4, 64);

    if ((lane & 31) == 0 && r < N) zn[r] = p * di;
}

// ---------------- layer 2 gather: 16 lanes per node ----------------
__global__ void k_gather2(const int* __restrict__ csrc, const int* __restrict__ counts,
                          const float* __restrict__ zn, const float* __restrict__ b2,
                          float* __restrict__ out, int N) {
    int t = blockIdx.x * blockDim.x + threadIdx.x;
    int r = t >> 4, li = t & 15;
    if (r >= N) return;
    size_t beg = (size_t)r * CAP;
    int cnt = counts[r];
    float acc = 0.f;
    for (int j = li; j < cnt; j += 16) {
        acc += zn[csrc[beg + j]];
    }
    acc += __shfl_xor(acc, 1, 64);
    acc += __shfl_xor(acc, 2, 64);
    acc += __shfl_xor(acc, 4, 64);
    acc += __shfl_xor(acc, 8, 64);
    if (li == 0) {
        float di = rsqrtf((float)(cnt + 1));
        out[r] = di * (acc + zn[r]) + b2[0];
    }
}

extern "C" void kernel_launch(void* const* d_in, const int* in_sizes, int n_in,
                              void* d_out, int out_size, void* d_ws, size_t ws_size,
                              hipStream_t stream) {
    const float* x  = (const float*)d_in[0];
    const int*   ei = (const int*)d_in[1];   // [2, E] int32
    const float* W1 = (const float*)d_in[2];
    const float* b1 = (const float*)d_in[3];
    const float* W2 = (const float*)d_in[4];
    const float* b2 = (const float*)d_in[5];
    float* out = (float*)d_out;

    const int N = in_sizes[0] / F_IN;     // 100000
    const int E = in_sizes[1] / 2;        // 1600000
    const int* src = ei;
    const int* dst = ei + E;

    const int nc = (N + CNODES - 1) / CNODES;   // 196 coarse buckets
    const int NBKT = (N + 63) / 64;             // 1563 gemm blocks

    // workspace layout (all 256B-aligned)
    char* ws = (char*)d_ws;
    size_t off = 0;
    auto alloc = [&](size_t bytes) { void* p = ws + off; off += (bytes + 255) & ~255ULL; return p; };
    int*    acur   = (int*)   alloc((size_t)nc * 4);
    int*    counts = (int*)   alloc((size_t)N * 4);
    float*  zn     = (float*) alloc((size_t)N * 4);
    unsigned short* W1hT = (unsigned short*) alloc((size_t)HID * F_IN * 2);  // 16 KB
    unsigned short* W1lT = (unsigned short*) alloc((size_t)HID * F_IN * 2);  // 16 KB
    int*    ent    = (int*)   alloc((size_t)nc * BCAPC * 4);  // 7.0 MB
    __half* hn     = (__half*)alloc((size_t)N * HID * 2);     // 12.8 MB
    int*    csrc   = (int*)   alloc((size_t)N * CAP * 4);     // 38.4 MB

    hipMemsetAsync(acur, 0, (size_t)nc * 4, stream);

    const int coarseBlks = (E + CCHUNK - 1) / CCHUNK;   // 391
    k_coarse<<<coarseBlks, 256, 0, stream>>>(src, dst, acur, ent, E, nc, W1, W1hT, W1lT);
    k_fillc<<<nc, 1024, 0, stream>>>(acur, ent, counts, csrc, N);
    k_gemm<<<NBKT, 256, 0, stream>>>(x, W1hT, W1lT, counts, hn, N);
    k_gather1<<<(N + 7) / 8, 256, 0, stream>>>(csrc, counts, hn, b1, W2, zn, N);
    k_gather2<<<((size_t)N * 16 + 255) / 256, 256, 0, stream>>>(csrc, counts, zn, b2, out, N);
}